// Round 1
// baseline (370.293 us; speedup 1.0000x reference)
//
#include <hip/hip_runtime.h>

// Problem constants
#define B_TOT 65536
#define WS_P1W 4096            // permuted bf16 p1W: 48*512*2 = 49152 B
#define WS_EV  (1u << 20)      // per-batch blocks: 512B E + 1024B V = 1536 B * 65536

typedef float f32x4 __attribute__((ext_vector_type(4)));
typedef short s16x8 __attribute__((ext_vector_type(8)));

__device__ __forceinline__ unsigned short f2bf(float f) {
    unsigned u = __builtin_bit_cast(unsigned, f);
    u += 0x7fffu + ((u >> 16) & 1u);   // round-to-nearest-even
    return (unsigned short)(u >> 16);
}
__device__ __forceinline__ float bf2f(unsigned short h) {
    unsigned u = ((unsigned)h) << 16;
    return __builtin_bit_cast(float, u);
}
__device__ __forceinline__ unsigned pack2(float a, float b) {
    return (unsigned)f2bf(a) | ((unsigned)f2bf(b) << 16);
}
__device__ __forceinline__ s16x8 cvt8(float4 a, float4 b) {
    s16x8 r;
    r[0] = (short)f2bf(a.x); r[1] = (short)f2bf(a.y);
    r[2] = (short)f2bf(a.z); r[3] = (short)f2bf(a.w);
    r[4] = (short)f2bf(b.x); r[5] = (short)f2bf(b.y);
    r[6] = (short)f2bf(b.z); r[7] = (short)f2bf(b.w);
    return r;
}
#define MFMA(a, b, c) __builtin_amdgcn_mfma_f32_16x16x32_bf16((a), (b), (c), 0, 0, 0)

// ---------------------------------------------------------------------------
// k0: zero the softmax denominators; build bf16 p1W permuted into the i' order
// that kernel2's H (hidden vector) uses.  i' = e_lo*32 + q*8 + h*4 + r, where
// original index = (q*4+r)*32 + (e_lo + 16*h).
// ---------------------------------------------------------------------------
__global__ __launch_bounds__(256) void k0_prep(const float* __restrict__ p1W,
                                               char* __restrict__ ws) {
    int idx = blockIdx.x * 256 + threadIdx.x;          // 96*256 = 24576 = 48*512
    if (blockIdx.x == 0 && threadIdx.x < 256)
        ((float*)ws)[threadIdx.x] = 0.f;               // D[256] accumulators
    int jj   = idx & 7;
    int lane = (idx >> 3) & 63;
    int ktnt = idx >> 9;
    int kt = ktnt & 15, nt = ktnt >> 4;
    int n_lo = lane & 15, q8 = lane >> 4;
    int j  = nt * 16 + n_lo;                           // output neuron [0,48)
    int ip = kt * 32 + q8 * 8 + jj;                    // i' in [0,512)
    int e_lo = ip >> 5, qq = (ip >> 3) & 3, hh = (ip >> 2) & 1, r = ip & 3;
    int orig = (qq * 4 + r) * 32 + (e_lo + 16 * hh);
    ((unsigned short*)(ws + WS_P1W))[idx] = f2bf(p1W[j * 512 + orig]);
}

// ---------------------------------------------------------------------------
// k1: per-batch Q,K,V linears (bf16 MFMA), normalize Q,K, S = Qn*Kn^T,
// E = exp(S) -> ws (layout [d][c] bf16), V -> ws (B-frag blocked bf16),
// global denominators D[d][c] via block-reduced atomics.
// One wave = one batch at a time; 16 batches/wave; 1024 blocks * 4 waves.
// ---------------------------------------------------------------------------
__global__ __launch_bounds__(256) void k1_stats(
    const float* __restrict__ e1, const float* __restrict__ e2,
    const float* __restrict__ qW, const float* __restrict__ qb,
    const float* __restrict__ kW, const float* __restrict__ kb,
    const float* __restrict__ vW, const float* __restrict__ vb,
    char* __restrict__ ws) {

    const int tid = threadIdx.x;
    const int lane = tid & 63;
    const int widx = tid >> 6;
    const int col = lane & 15;      // n-index (e_lo / d) in MFMA layouts
    const int quad = lane >> 4;

    __shared__ __align__(16) unsigned short qk_lds[4][2][16 * 40]; // padded rows (40 bf16 = 80B)
    __shared__ float Dblk[256];
    Dblk[tid] = 0.f;
    __syncthreads();

    // Weight B-fragments: B_h[k=l][n=e_lo] = W[e_lo+16h][l], lane holds 8 consecutive l.
    s16x8 wq[2], wk[2], wv[2];
    float qbias[2], kbias[2], vbias[2];
    for (int h = 0; h < 2; ++h) {
        int row = col + 16 * h;
        const float4* pq = (const float4*)(qW + row * 32 + quad * 8);
        const float4* pk = (const float4*)(kW + row * 32 + quad * 8);
        const float4* pv = (const float4*)(vW + row * 32 + quad * 8);
        wq[h] = cvt8(pq[0], pq[1]);
        wk[h] = cvt8(pk[0], pk[1]);
        wv[h] = cvt8(pv[0], pv[1]);
        qbias[h] = qb[row]; kbias[h] = kb[row]; vbias[h] = vb[row];
    }

    unsigned short* qbuf = qk_lds[widx][0];
    unsigned short* kbuf = qk_lds[widx][1];
    float dacc[4] = {0.f, 0.f, 0.f, 0.f};
    char* evbase = ws + WS_EV;
    const f32x4 z = {0.f, 0.f, 0.f, 0.f};

    const int gw = blockIdx.x * 4 + widx;
    for (int i = 0; i < 16; ++i) {
        const int b = gw * 16 + i;
        // A-fragments of X1, X2: lane holds X[c=col][l = quad*8 .. +7]
        const float4* x1p = (const float4*)(e1 + (size_t)b * 512 + col * 32 + quad * 8);
        const float4* x2p = (const float4*)(e2 + (size_t)b * 512 + col * 32 + quad * 8);
        float4 a0 = x1p[0], a1 = x1p[1];
        float4 b0 = x2p[0], b1 = x2p[1];
        s16x8 fx1 = cvt8(a0, a1);
        s16x8 fx2 = cvt8(b0, b1);

        f32x4 q1[2], q2[2], k1[2], k2[2], v1[2], v2[2];
        for (int h = 0; h < 2; ++h) {
            q1[h] = MFMA(fx1, wq[h], z); q2[h] = MFMA(fx2, wq[h], z);
            k1[h] = MFMA(fx1, wk[h], z); k2[h] = MFMA(fx2, wk[h], z);
            v1[h] = MFMA(fx1, wv[h], z); v2[h] = MFMA(fx2, wv[h], z);
        }
        // products + bias; C/D layout: value (h,r) = M[row=quad*4+r][e=col+16h]
        float Qt[2][4], Kt[2][4], Vv[2][4];
        for (int h = 0; h < 2; ++h)
            for (int r = 0; r < 4; ++r) {
                Qt[h][r] = (q1[h][r] + qbias[h]) * (q2[h][r] + qbias[h]);
                Kt[h][r] = (k1[h][r] + kbias[h]) * (k2[h][r] + kbias[h]);
                Vv[h][r] = (v1[h][r] + vbias[h]) * (v2[h][r] + vbias[h]);
            }
        // LDS rows store permuted e' = e_lo*2 + h (pairs packable, perm shared by Q,K)
        for (int r = 0; r < 4; ++r) {
            int w = (quad * 4 + r) * 20 + col;   // uint index, row stride 20 words
            ((unsigned*)qbuf)[w] = pack2(Qt[0][r], Qt[1][r]);
            ((unsigned*)kbuf)[w] = pack2(Kt[0][r], Kt[1][r]);
        }
        // Read back as A (Q) / B (K) fragments: lane = row col, chunk quad*8
        s16x8 aq = *(const s16x8*)(qbuf + col * 40 + quad * 8);
        s16x8 bk = *(const s16x8*)(kbuf + col * 40 + quad * 8);
        float qv[8], kv[8], ssq = 0.f, ssk = 0.f;
        for (int j = 0; j < 8; ++j) {
            qv[j] = bf2f((unsigned short)aq[j]); ssq += qv[j] * qv[j];
            kv[j] = bf2f((unsigned short)bk[j]); ssk += kv[j] * kv[j];
        }
        ssq += __shfl_xor(ssq, 16); ssq += __shfl_xor(ssq, 32);
        ssk += __shfl_xor(ssk, 16); ssk += __shfl_xor(ssk, 32);
        float sq = 1.f / fmaxf(sqrtf(ssq), 1e-12f);
        float sk = 1.f / fmaxf(sqrtf(ssk), 1e-12f);
        for (int j = 0; j < 8; ++j) {
            aq[j] = (short)f2bf(qv[j] * sq);
            bk[j] = (short)f2bf(kv[j] * sk);
        }
        f32x4 S = MFMA(aq, bk, z);   // S[c=quad*4+r][d=col]

        char* bbase = evbase + (size_t)b * 1536;
        float ex[4];
        for (int r = 0; r < 4; ++r) { ex[r] = __expf(S[r]); dacc[r] += ex[r]; }
        // E stored [d][c] bf16: lane covers c = quad*4 .. +3 at row d=col
        uint2 est; est.x = pack2(ex[0], ex[1]); est.y = pack2(ex[2], ex[3]);
        *(uint2*)(bbase + col * 32 + quad * 8) = est;
        // V stored blocked for k2 B-frags: block(h, e_lo=col, c-half quad>>1)
        for (int h = 0; h < 2; ++h) {
            uint2 vst;
            vst.x = pack2(Vv[h][0], Vv[h][1]);
            vst.y = pack2(Vv[h][2], Vv[h][3]);
            *(uint2*)(bbase + 512 + ((h * 16 + col) * 2 + (quad >> 1)) * 16 + (quad & 1) * 8) = vst;
        }
    }
    // Hierarchical denominator reduce: regs -> block LDS -> global atomics
    for (int r = 0; r < 4; ++r)
        atomicAdd(&Dblk[col * 16 + quad * 4 + r], dacc[r]);
    __syncthreads();
    atomicAdd(((float*)ws) + tid, Dblk[tid]);
}

// ---------------------------------------------------------------------------
// k2: per-batch out = P^T V (MFMA, K padded to 32), H -> per-wave LDS
// (XOR-swizzled chunks), MLP1 via MFMA batched over 16 b's, MLP2 + normalize
// via shuffles.  One wave = one 16-batch group; 1024 blocks * 4 waves.
// ---------------------------------------------------------------------------
__global__ __launch_bounds__(256) void k2_apply(
    const char* __restrict__ ws, const float* __restrict__ p1b,
    const float* __restrict__ p2W, const float* __restrict__ p2b,
    float* __restrict__ out) {

    const int tid = threadIdx.x;
    const int lane = tid & 63;
    const int widx = tid >> 6;
    const int col = lane & 15;
    const int quad = lane >> 4;
    const int qm = quad & 1;        // mirrored address for upper quads

    __shared__ __align__(16) unsigned short H[4][16 * 512];  // 64 KiB exactly
    unsigned short* hrow = H[widx];

    // 1/denominator, transposed layout matching E A-frag: dinv[jj] for c=quad*8+jj
    const float* Dws = (const float*)ws;
    float dinv[8];
    for (int j = 0; j < 8; ++j)
        dinv[j] = 1.f / Dws[col * 16 + qm * 8 + j];

    float p2w[3][3], p1bias[3];
    for (int nt = 0; nt < 3; ++nt) {
        p1bias[nt] = p1b[col + 16 * nt];
        for (int t = 0; t < 3; ++t) p2w[nt][t] = p2W[t * 48 + col + 16 * nt];
    }
    const float pb0 = p2b[0], pb1 = p2b[1], pb2 = p2b[2];

    const char* evbase = ws + WS_EV;
    const unsigned short* p1wp = (const unsigned short*)(ws + WS_P1W);
    const int g = blockIdx.x * 4 + widx;
    const f32x4 z = {0.f, 0.f, 0.f, 0.f};
    const s16x8 zz = {0, 0, 0, 0, 0, 0, 0, 0};

    // Phase 1: out[d][e] per batch -> H rows (bf16, swizzled)
#pragma unroll 4
    for (int i = 0; i < 16; ++i) {
        const int b = g * 16 + i;
        const char* bbase = evbase + (size_t)b * 1536;
        s16x8 eraw = *(const s16x8*)(bbase + col * 32 + qm * 16);
        s16x8 bf0 = *(const s16x8*)(bbase + 512 + (col * 2 + qm) * 16);
        s16x8 bf1 = *(const s16x8*)(bbase + 512 + ((16 + col) * 2 + qm) * 16);
        s16x8 afrag;
        for (int j = 0; j < 8; ++j)
            afrag[j] = (short)f2bf(bf2f((unsigned short)eraw[j]) * dinv[j]);
        if (quad >= 2) { afrag = zz; bf0 = zz; bf1 = zz; }  // K-padding (c>=16 -> 0)
        f32x4 o0 = MFMA(afrag, bf0, z);   // out[d=quad*4+r][e=col]
        f32x4 o1 = MFMA(afrag, bf1, z);   // out[d=quad*4+r][e=col+16]
        s16x8 hp;
        for (int r = 0; r < 4; ++r) {
            hp[r]     = (short)f2bf(o0[r]);
            hp[4 + r] = (short)f2bf(o1[r]);
        }
        int chunk = (col * 4 + quad) ^ (i & 7);   // 16B-chunk XOR swizzle
        *(s16x8*)(hrow + i * 512 + chunk * 8) = hp;
    }

    // Phase 2: MLP1 — H[16 x 512] @ p1Wp^T -> h1[16 x 48] via MFMA
    f32x4 acc[3] = {z, z, z};
#pragma unroll 4
    for (int kt = 0; kt < 16; ++kt) {
        int chunk = (kt * 4 + quad) ^ (col & 7);
        s16x8 a = *(const s16x8*)(hrow + col * 512 + chunk * 8);
        for (int nt = 0; nt < 3; ++nt) {
            s16x8 bw = *(const s16x8*)(p1wp + ((nt * 16 + kt) * 64 + lane) * 8);
            acc[nt] = MFMA(a, bw, acc[nt]);
        }
    }

    // Phase 3: bias+relu, MLP2 partials, 16-lane butterfly, normalize, store
    float pp[4][3] = {};
    for (int nt = 0; nt < 3; ++nt)
        for (int r = 0; r < 4; ++r) {
            float hv = fmaxf(acc[nt][r] + p1bias[nt], 0.f);
            pp[r][0] += hv * p2w[nt][0];
            pp[r][1] += hv * p2w[nt][1];
            pp[r][2] += hv * p2w[nt][2];
        }
    for (int m = 1; m <= 8; m <<= 1)
        for (int r = 0; r < 4; ++r)
            for (int t = 0; t < 3; ++t)
                pp[r][t] += __shfl_xor(pp[r][t], m);
    for (int r = 0; r < 4; ++r) {
        float h0 = pp[r][0] + pb0, h1 = pp[r][1] + pb1, h2 = pp[r][2] + pb2;
        float inv = 1.f / fmaxf(sqrtf(h0 * h0 + h1 * h1 + h2 * h2), 1e-12f);
        if (col < 3) {
            float v = (col == 0) ? h0 : ((col == 1) ? h1 : h2);
            out[(size_t)(g * 16 + quad * 4 + r) * 3 + col] = v * inv;
        }
    }
}

// ---------------------------------------------------------------------------
extern "C" void kernel_launch(void* const* d_in, const int* in_sizes, int n_in,
                              void* d_out, int out_size, void* d_ws, size_t ws_size,
                              hipStream_t stream) {
    const float* e1  = (const float*)d_in[0];
    const float* e2  = (const float*)d_in[1];
    const float* qW  = (const float*)d_in[2];
    const float* qb  = (const float*)d_in[3];
    const float* kW  = (const float*)d_in[4];
    const float* kb  = (const float*)d_in[5];
    const float* vW  = (const float*)d_in[6];
    const float* vb  = (const float*)d_in[7];
    const float* p1W = (const float*)d_in[8];
    const float* p1b = (const float*)d_in[9];
    const float* p2W = (const float*)d_in[10];
    const float* p2b = (const float*)d_in[11];
    float* out = (float*)d_out;
    char* ws = (char*)d_ws;

    k0_prep<<<96, 256, 0, stream>>>(p1W, ws);
    k1_stats<<<1024, 256, 0, stream>>>(e1, e2, qW, qb, kW, kb, vW, vb, ws);
    k2_apply<<<1024, 256, 0, stream>>>(ws, p1b, p2W, p2b, out);
}

// Round 2
// 342.205 us; speedup vs baseline: 1.0821x; 1.0821x over previous
//
#include <hip/hip_runtime.h>

// Problem constants
#define B_TOT 65536
#define WS_P1W 4096            // permuted bf16 p1W: 48*512*2 = 49152 B
#define WS_EV  (1u << 20)      // per-batch blocks: 512B E + 1024B V = 1536 B * 65536

typedef float f32x4 __attribute__((ext_vector_type(4)));
typedef short s16x8 __attribute__((ext_vector_type(8)));

__device__ __forceinline__ float bf2f(unsigned short h) {
    unsigned u = ((unsigned)h) << 16;
    return __builtin_bit_cast(float, u);
}
// cheap bf16 pair pack: round-half-up (add 0x8000) + v_perm_b32 high-half merge.
// 3 VALU ops per pair vs ~9 for RNE; bias is negligible at our error budget.
__device__ __forceinline__ unsigned pack2(float a, float b) {
    unsigned ua = __builtin_bit_cast(unsigned, a) + 0x8000u;
    unsigned ub = __builtin_bit_cast(unsigned, b) + 0x8000u;
    return __builtin_amdgcn_perm(ub, ua, 0x07060302u);  // lo16=a, hi16=b
}
__device__ __forceinline__ unsigned short f2bf(float f) {
    return (unsigned short)((__builtin_bit_cast(unsigned, f) + 0x8000u) >> 16);
}
__device__ __forceinline__ s16x8 cvt8(float4 a, float4 b) {
    uint4 u;
    u.x = pack2(a.x, a.y); u.y = pack2(a.z, a.w);
    u.z = pack2(b.x, b.y); u.w = pack2(b.z, b.w);
    return __builtin_bit_cast(s16x8, u);
}
#define MFMA(a, b, c) __builtin_amdgcn_mfma_f32_16x16x32_bf16((a), (b), (c), 0, 0, 0)

// ---------------------------------------------------------------------------
// k0: zero the softmax denominators; build bf16 p1W permuted into the i' order
// that kernel2's H (hidden vector) uses.  i' = e_lo*32 + q*8 + h*4 + r, where
// original index = (q*4+r)*32 + (e_lo + 16*h).
// ---------------------------------------------------------------------------
__global__ __launch_bounds__(256) void k0_prep(const float* __restrict__ p1W,
                                               char* __restrict__ ws) {
    int idx = blockIdx.x * 256 + threadIdx.x;          // 96*256 = 24576 = 48*512
    if (blockIdx.x == 0 && threadIdx.x < 256)
        ((float*)ws)[threadIdx.x] = 0.f;               // D[256] accumulators
    int jj   = idx & 7;
    int lane = (idx >> 3) & 63;
    int ktnt = idx >> 9;
    int kt = ktnt & 15, nt = ktnt >> 4;
    int n_lo = lane & 15, q8 = lane >> 4;
    int j  = nt * 16 + n_lo;                           // output neuron [0,48)
    int ip = kt * 32 + q8 * 8 + jj;                    // i' in [0,512)
    int e_lo = ip >> 5, qq = (ip >> 3) & 3, hh = (ip >> 2) & 1, r = ip & 3;
    int orig = (qq * 4 + r) * 32 + (e_lo + 16 * hh);
    ((unsigned short*)(ws + WS_P1W))[idx] = f2bf(p1W[j * 512 + orig]);
}

// ---------------------------------------------------------------------------
// k1: per-batch Q,K,V linears (bf16 MFMA, bias folded into accumulator),
// normalize Q,K, S = Qn*Kn^T, E=exp(S) -> ws ([d][c] bf16), V -> ws (B-frag
// blocked bf16), global denominators D[d][c] via block-reduced atomics.
// 8 batches/wave, 2048 blocks * 4 waves -> 8 blocks/CU -> 32 waves/CU.
// ---------------------------------------------------------------------------
__global__ __launch_bounds__(256) void k1_stats(
    const float* __restrict__ e1, const float* __restrict__ e2,
    const float* __restrict__ qW, const float* __restrict__ qb,
    const float* __restrict__ kW, const float* __restrict__ kb,
    const float* __restrict__ vW, const float* __restrict__ vb,
    char* __restrict__ ws) {

    const int tid = threadIdx.x;
    const int lane = tid & 63;
    const int widx = tid >> 6;
    const int col = lane & 15;      // n-index (e_lo / d) in MFMA layouts
    const int quad = lane >> 4;

    __shared__ __align__(16) unsigned short qk_lds[4][2][16 * 40]; // padded rows (80B)
    __shared__ float Dblk[256];
    Dblk[tid] = 0.f;
    __syncthreads();

    // Weight B-fragments: B_h[k=l][n=e_lo] = W[e_lo+16h][l], lane holds 8 consecutive l.
    s16x8 wq[2], wk[2], wv[2];
    f32x4 cbq[2], cbk[2], cbv[2];   // bias pre-loaded into MFMA accumulators
    for (int h = 0; h < 2; ++h) {
        int row = col + 16 * h;
        const float4* pq = (const float4*)(qW + row * 32 + quad * 8);
        const float4* pk = (const float4*)(kW + row * 32 + quad * 8);
        const float4* pv = (const float4*)(vW + row * 32 + quad * 8);
        wq[h] = cvt8(pq[0], pq[1]);
        wk[h] = cvt8(pk[0], pk[1]);
        wv[h] = cvt8(pv[0], pv[1]);
        float qv = qb[row], kv = kb[row], vv = vb[row];
        cbq[h] = (f32x4){qv, qv, qv, qv};
        cbk[h] = (f32x4){kv, kv, kv, kv};
        cbv[h] = (f32x4){vv, vv, vv, vv};
    }

    unsigned short* qbuf = qk_lds[widx][0];
    unsigned short* kbuf = qk_lds[widx][1];
    float dacc[4] = {0.f, 0.f, 0.f, 0.f};
    char* evbase = ws + WS_EV;
    const f32x4 z = {0.f, 0.f, 0.f, 0.f};

    const int gw = blockIdx.x * 4 + widx;
    for (int i = 0; i < 8; ++i) {
        const int b = gw * 8 + i;
        // A-fragments of X1, X2: lane holds X[c=col][l = quad*8 .. +7]
        const float4* x1p = (const float4*)(e1 + (size_t)b * 512 + col * 32 + quad * 8);
        const float4* x2p = (const float4*)(e2 + (size_t)b * 512 + col * 32 + quad * 8);
        float4 a0 = x1p[0], a1 = x1p[1];
        float4 b0 = x2p[0], b1 = x2p[1];
        s16x8 fx1 = cvt8(a0, a1);
        s16x8 fx2 = cvt8(b0, b1);

        f32x4 q1[2], q2[2], k1[2], k2[2], v1[2], v2[2];
        for (int h = 0; h < 2; ++h) {
            q1[h] = MFMA(fx1, wq[h], cbq[h]); q2[h] = MFMA(fx2, wq[h], cbq[h]);
            k1[h] = MFMA(fx1, wk[h], cbk[h]); k2[h] = MFMA(fx2, wk[h], cbk[h]);
            v1[h] = MFMA(fx1, wv[h], cbv[h]); v2[h] = MFMA(fx2, wv[h], cbv[h]);
        }
        // products; C/D layout: value (h,r) = M[row=quad*4+r][e=col+16h]
        float Qt[2][4], Kt[2][4], Vv[2][4];
        for (int h = 0; h < 2; ++h)
            for (int r = 0; r < 4; ++r) {
                Qt[h][r] = q1[h][r] * q2[h][r];
                Kt[h][r] = k1[h][r] * k2[h][r];
                Vv[h][r] = v1[h][r] * v2[h][r];
            }
        // LDS rows store permuted e' = e_lo*2 + h (pairs packable, perm shared by Q,K)
        for (int r = 0; r < 4; ++r) {
            int w = (quad * 4 + r) * 20 + col;   // uint index, row stride 20 words
            ((unsigned*)qbuf)[w] = pack2(Qt[0][r], Qt[1][r]);
            ((unsigned*)kbuf)[w] = pack2(Kt[0][r], Kt[1][r]);
        }
        // Read back as A (Q) / B (K) fragments: lane = row col, chunk quad*8
        s16x8 aq = *(const s16x8*)(qbuf + col * 40 + quad * 8);
        s16x8 bk = *(const s16x8*)(kbuf + col * 40 + quad * 8);
        float qv[8], kv[8], ssq = 0.f, ssk = 0.f;
        for (int j = 0; j < 8; ++j) {
            qv[j] = bf2f((unsigned short)aq[j]); ssq += qv[j] * qv[j];
            kv[j] = bf2f((unsigned short)bk[j]); ssk += kv[j] * kv[j];
        }
        ssq += __shfl_xor(ssq, 16); ssq += __shfl_xor(ssq, 32);
        ssk += __shfl_xor(ssk, 16); ssk += __shfl_xor(ssk, 32);
        float sq = 1.f / fmaxf(sqrtf(ssq), 1e-12f);
        float sk = 1.f / fmaxf(sqrtf(ssk), 1e-12f);
        uint4 uq, uk;
        uq.x = pack2(qv[0] * sq, qv[1] * sq); uq.y = pack2(qv[2] * sq, qv[3] * sq);
        uq.z = pack2(qv[4] * sq, qv[5] * sq); uq.w = pack2(qv[6] * sq, qv[7] * sq);
        uk.x = pack2(kv[0] * sk, kv[1] * sk); uk.y = pack2(kv[2] * sk, kv[3] * sk);
        uk.z = pack2(kv[4] * sk, kv[5] * sk); uk.w = pack2(kv[6] * sk, kv[7] * sk);
        aq = __builtin_bit_cast(s16x8, uq);
        bk = __builtin_bit_cast(s16x8, uk);
        f32x4 S = MFMA(aq, bk, z);   // S[c=quad*4+r][d=col]

        char* bbase = evbase + (size_t)b * 1536;
        float ex[4];
        for (int r = 0; r < 4; ++r) { ex[r] = __expf(S[r]); dacc[r] += ex[r]; }
        // E stored [d][c] bf16: lane covers c = quad*4 .. +3 at row d=col
        uint2 est; est.x = pack2(ex[0], ex[1]); est.y = pack2(ex[2], ex[3]);
        *(uint2*)(bbase + col * 32 + quad * 8) = est;
        // V stored blocked for k2 B-frags: block(h, e_lo=col, c-half quad>>1)
        for (int h = 0; h < 2; ++h) {
            uint2 vst;
            vst.x = pack2(Vv[h][0], Vv[h][1]);
            vst.y = pack2(Vv[h][2], Vv[h][3]);
            *(uint2*)(bbase + 512 + ((h * 16 + col) * 2 + (quad >> 1)) * 16 + (quad & 1) * 8) = vst;
        }
    }
    // Hierarchical denominator reduce: regs -> block LDS -> global atomics
    for (int r = 0; r < 4; ++r)
        atomicAdd(&Dblk[col * 16 + quad * 4 + r], dacc[r]);
    __syncthreads();
    atomicAdd(((float*)ws) + tid, Dblk[tid]);
}

// ---------------------------------------------------------------------------
// k2: cooperative 4-wave block over ONE 16-batch group.  Phase1: each wave
// computes 4 of the 16 per-batch out[d][e] rows into a shared 16KB H (bf16,
// XOR-swizzled chunks).  Phase2: each wave takes 4 of the 16 k-tiles of
// MLP1 (MFMA), partial accs reduced through LDS (aliased over H).  Phase3:
// wave 0 does bias+relu, MLP2, normalize, store.  16KB LDS -> 8 blocks/CU
// -> 32 waves/CU (was 8).  Grid 4096 blocks.
// ---------------------------------------------------------------------------
__global__ __launch_bounds__(256) void k2_apply(
    const char* __restrict__ ws, const float* __restrict__ p1b,
    const float* __restrict__ p2W, const float* __restrict__ p2b,
    float* __restrict__ out) {

    const int tid = threadIdx.x;
    const int lane = tid & 63;
    const int widx = tid >> 6;
    const int col = lane & 15;
    const int quad = lane >> 4;
    const int qm = quad & 1;        // mirrored address for upper quads

    __shared__ __align__(16) unsigned short Hs[16 * 512];   // 16 KiB
    float* P = (float*)Hs;          // aliased partial-sum buffer (12 KiB <= 16 KiB)

    // 1/denominator, transposed layout matching E A-frag: dinv[j] for c=qm*8+j
    const float* Dws = (const float*)ws;
    float dinv[8];
    for (int j = 0; j < 8; ++j)
        dinv[j] = 1.f / Dws[col * 16 + qm * 8 + j];

    const char* evbase = ws + WS_EV;
    const unsigned short* p1wp = (const unsigned short*)(ws + WS_P1W);
    const int g = blockIdx.x;
    const f32x4 z = {0.f, 0.f, 0.f, 0.f};
    const s16x8 zz = {0, 0, 0, 0, 0, 0, 0, 0};

    // Phase 1: out[d][e] for batches i = widx*4 .. +3 -> H rows (bf16, swizzled)
    for (int ii = 0; ii < 4; ++ii) {
        const int i = widx * 4 + ii;
        const int b = g * 16 + i;
        const char* bbase = evbase + (size_t)b * 1536;
        s16x8 eraw = *(const s16x8*)(bbase + col * 32 + qm * 16);
        s16x8 bf0 = *(const s16x8*)(bbase + 512 + (col * 2 + qm) * 16);
        s16x8 bf1 = *(const s16x8*)(bbase + 512 + ((16 + col) * 2 + qm) * 16);
        float ef[8];
        for (int j = 0; j < 8; ++j)
            ef[j] = bf2f((unsigned short)eraw[j]) * dinv[j];
        uint4 ua;
        ua.x = pack2(ef[0], ef[1]); ua.y = pack2(ef[2], ef[3]);
        ua.z = pack2(ef[4], ef[5]); ua.w = pack2(ef[6], ef[7]);
        s16x8 afrag = __builtin_bit_cast(s16x8, ua);
        if (quad >= 2) { afrag = zz; bf0 = zz; bf1 = zz; }  // K-padding (c>=16 -> 0)
        f32x4 o0 = MFMA(afrag, bf0, z);   // out[d=quad*4+r][e=col]
        f32x4 o1 = MFMA(afrag, bf1, z);   // out[d=quad*4+r][e=col+16]
        uint4 uh;
        uh.x = pack2(o0[0], o0[1]); uh.y = pack2(o0[2], o0[3]);
        uh.z = pack2(o1[0], o1[1]); uh.w = pack2(o1[2], o1[3]);
        int chunk = (col * 4 + quad) ^ (i & 7);   // 16B-chunk XOR swizzle
        *(uint4*)(Hs + i * 512 + chunk * 8) = uh;
    }
    __syncthreads();

    // Phase 2: MLP1 — H[16 x 512] @ p1Wp^T, wave widx handles kt = widx*4..+3
    f32x4 acc[3] = {z, z, z};
    for (int t = 0; t < 4; ++t) {
        int kt = widx * 4 + t;
        int chunk = (kt * 4 + quad) ^ (col & 7);
        s16x8 a = *(const s16x8*)(Hs + col * 512 + chunk * 8);
        for (int nt = 0; nt < 3; ++nt) {
            s16x8 bw = *(const s16x8*)(p1wp + ((nt * 16 + kt) * 64 + lane) * 8);
            acc[nt] = MFMA(a, bw, acc[nt]);
        }
    }
    __syncthreads();   // H reads done before P overwrites it

    // partials -> LDS: P[widx][lane][nt*4+r], lane stride 12 floats (48B)
    for (int nt = 0; nt < 3; ++nt)
        *(f32x4*)(P + (widx * 64 + lane) * 12 + nt * 4) = acc[nt];
    __syncthreads();

    if (widx == 0) {
        // Phase 3: sum partials, bias+relu, MLP2, 16-lane butterfly, normalize
        f32x4 s[3] = {z, z, z};
        for (int w = 0; w < 4; ++w)
            for (int nt = 0; nt < 3; ++nt) {
                f32x4 pv = *(const f32x4*)(P + (w * 64 + lane) * 12 + nt * 4);
                s[nt] += pv;
            }
        float p2w[3][3], p1bias[3];
        for (int nt = 0; nt < 3; ++nt) {
            p1bias[nt] = p1b[col + 16 * nt];
            for (int t = 0; t < 3; ++t) p2w[nt][t] = p2W[t * 48 + col + 16 * nt];
        }
        const float pb0 = p2b[0], pb1 = p2b[1], pb2 = p2b[2];
        float pp[4][3] = {};
        for (int nt = 0; nt < 3; ++nt)
            for (int r = 0; r < 4; ++r) {
                float hv = fmaxf(s[nt][r] + p1bias[nt], 0.f);
                pp[r][0] += hv * p2w[nt][0];
                pp[r][1] += hv * p2w[nt][1];
                pp[r][2] += hv * p2w[nt][2];
            }
        for (int m = 1; m <= 8; m <<= 1)
            for (int r = 0; r < 4; ++r)
                for (int t = 0; t < 3; ++t)
                    pp[r][t] += __shfl_xor(pp[r][t], m);
        for (int r = 0; r < 4; ++r) {
            float h0 = pp[r][0] + pb0, h1 = pp[r][1] + pb1, h2 = pp[r][2] + pb2;
            float inv = 1.f / fmaxf(sqrtf(h0 * h0 + h1 * h1 + h2 * h2), 1e-12f);
            if (col < 3) {
                float v = (col == 0) ? h0 : ((col == 1) ? h1 : h2);
                out[(size_t)(g * 16 + quad * 4 + r) * 3 + col] = v * inv;
            }
        }
    }
}

// ---------------------------------------------------------------------------
extern "C" void kernel_launch(void* const* d_in, const int* in_sizes, int n_in,
                              void* d_out, int out_size, void* d_ws, size_t ws_size,
                              hipStream_t stream) {
    const float* e1  = (const float*)d_in[0];
    const float* e2  = (const float*)d_in[1];
    const float* qW  = (const float*)d_in[2];
    const float* qb  = (const float*)d_in[3];
    const float* kW  = (const float*)d_in[4];
    const float* kb  = (const float*)d_in[5];
    const float* vW  = (const float*)d_in[6];
    const float* vb  = (const float*)d_in[7];
    const float* p1W = (const float*)d_in[8];
    const float* p1b = (const float*)d_in[9];
    const float* p2W = (const float*)d_in[10];
    const float* p2b = (const float*)d_in[11];
    float* out = (float*)d_out;
    char* ws = (char*)d_ws;

    k0_prep<<<96, 256, 0, stream>>>(p1W, ws);
    k1_stats<<<2048, 256, 0, stream>>>(e1, e2, qW, qb, kW, kb, vW, vb, ws);
    k2_apply<<<4096, 256, 0, stream>>>(ws, p1b, p2W, p2b, out);
}